// Round 10
// baseline (269.041 us; speedup 1.0000x reference)
//
#include <hip/hip_runtime.h>

#define TOK 65536
#define DM 256
#define DF 1024
#define NB 4

typedef unsigned short ushort_t;
typedef unsigned int uint32;

typedef __attribute__((ext_vector_type(8))) short bf16x8;
typedef __attribute__((ext_vector_type(4))) float f32x4;
typedef __attribute__((ext_vector_type(4))) uint32 u32x4;

__device__ inline ushort_t f2bf(float f) {
  union { float f; unsigned int u; } v; v.f = f;
  unsigned int u = v.u;
  unsigned int r = (u + 0x7FFFu + ((u >> 16) & 1u)) >> 16;
  return (ushort_t)r;
}
__device__ inline float bf2f(ushort_t u) {
  union { unsigned int u; float f; } v; v.u = ((uint32)u) << 16; return v.f;
}
__device__ inline uint32 pack2(float a, float b) {
  return (uint32)f2bf(a) | ((uint32)f2bf(b) << 16);
}

// ------- kernel 0: merged route + W1/W2 -> fragment-layout conversion ------
// blocks [0,256): route (counts pre-zeroed via hipMemsetAsync)
// blocks [256,768): W1 -> W1f frag layout (verified round 6/9):
//  W1f[((n*32+fc)*2+fi)*8+ks][lane(q,lc)][j] = W1[n][fc*32+fi*16+lc][ks*32+q*8+j]
// blocks [768,1280): W2 -> W2f frag layout (verified rounds 6-9):
//  W2f[((fc*4+dq)*4+di)*512 + lane*8 + j] (per branch) =
//      W2[n][dq*64+di*16+(lane&15)][fc*32+(lane>>4)*8+j]
__global__ __launch_bounds__(256) void prep_route_kernel(
    const float* __restrict__ w1, const float* __restrict__ w2,
    ushort_t* __restrict__ w1fb, ushort_t* __restrict__ w2fb,
    const int* __restrict__ b_seq, int* __restrict__ counts,
    ushort_t* __restrict__ lists, u32x4* __restrict__ out16)
{
  const int bx = blockIdx.x;
  const int tid = threadIdx.x;
  if (bx >= 256) {
    const bool isw2 = bx >= 768;
    const int gid = (bx - (isw2 ? 768 : 256)) * 256 + tid;   // 0..131071
    const int lane_ = gid & 63;
    const int lcq = lane_ & 15, qq = lane_ >> 4;
    size_t src_off;
    if (!isw2) {
      int ks = (gid >> 6) & 7, fi = (gid >> 9) & 1;
      int fc = (gid >> 10) & 31, nn = gid >> 15;
      src_off = (size_t)(nn * 1024 + fc * 32 + fi * 16 + lcq) * 256 + ks * 32 + qq * 8;
    } else {
      int di = (gid >> 6) & 3, dqv = (gid >> 8) & 3;
      int fc = (gid >> 10) & 31, nn = gid >> 15;
      src_off = (size_t)(nn * 256 + dqv * 64 + di * 16 + lcq) * 1024 + fc * 32 + qq * 8;
    }
    const float* src = (isw2 ? w2 : w1) + src_off;
    f32x4 a = *(const f32x4*)src;
    f32x4 c = *(const f32x4*)(src + 4);
    u32x4 p;
    p.x = pack2(a.x, a.y); p.y = pack2(a.z, a.w);
    p.z = pack2(c.x, c.y); p.w = pack2(c.z, c.w);
    ushort_t* dst = isw2 ? w2fb : w1fb;
    *(u32x4*)(dst + (size_t)gid * 8) = p;
    return;
  }
  // ---- route branch
  __shared__ int s_lpos[NB];
  __shared__ int s_lbase[NB];
  __shared__ int s_b[256];
  const int base = bx * 256;
  const int token = base + tid;
  if (tid < NB) s_lpos[tid] = 0;
  __syncthreads();
  const int b = b_seq[token];
  s_b[tid] = b;
  int my = 0;
  if (b > 0) my = atomicAdd(&s_lpos[b - 1], 1);
  __syncthreads();
  if (tid < NB) s_lbase[tid] = atomicAdd(&counts[tid], s_lpos[tid]);
  __syncthreads();
  if (b > 0) lists[(b - 1) * TOK + s_lbase[b - 1] + my] = (ushort_t)token;
  const u32x4 z = (u32x4){0u, 0u, 0u, 0u};
  #pragma unroll 4
  for (int it = 0; it < 64; ++it) {
    int flat = it * 256 + tid;
    int tl = flat >> 6;
    int j = flat & 63;
    if (s_b[tl] == 0) out16[(size_t)(base + tl) * 64 + j] = z;
  }
}

// ---------------- kernel 1: FFN + LN, weights direct-from-L2 (ordered) -----
// Round-9 lesson: vmcnt is IN-ORDER — a consumer's wait drains everything
// YOUNGER. r9 put W2 JIT loads (newest) inside g2 -> vmcnt(0) drained the
// w1 prefetch every chunk (~400cy exposed, +56us). This round restores r8's
// proven discipline: prefetches for the NEXT consumer always issue BEFORE
// same-iteration consumed loads. Steady-state per iter i (verified chain):
//   w2load(i-1) [4, oldest] -> g1(i) waits w1r: vmcnt(4), leaves w2r;
//   w1load(i+1) [8, newest] -> g2(i-1) waits w2r: vmcnt(8), leaves w1r
//   in flight across the lgkm-only barrier (no DMA -> no vmcnt drain ever).
// sched_barrier(0) fences pin this order against scheduler hoisting.
// LDS/chunk: ~350 cyc (af reads + sH writes only; was ~1030 in r8).
// Regs: xfrag 32 + w1r 32 (only cross-barrier vmem pinning) + w2r 16 +
// yacc 32 AGPR ~ 112-126 unified <= 128 cap (r9 measured 96 w/o w2r).
// Block = 8 waves (512 thr), M=64 tokens, 32 chunks of F=32.
//  GEMM1 wave (fi=wv&1, mq=wv>>1): 16 tok x 16 f.
//  GEMM2 wave (dq=wv&3, mh=wv>>2): 32 tok x 64 d.
__global__ __launch_bounds__(512, 4) void ffn_kernel(
    const float* __restrict__ x,
    const ushort_t* __restrict__ w1f_all, const float* __restrict__ b1,
    const ushort_t* __restrict__ w2f_all, const float* __restrict__ b2,
    const float* __restrict__ gamma, const float* __restrict__ beta,
    const int* __restrict__ counts, const ushort_t* __restrict__ lists,
    float* __restrict__ out)
{
  const int id = blockIdx.x;
  const int slot = id & 7;            // XCD affinity: branch n -> XCDs {2n,2n+1}
  const int n = slot >> 1;
  const int tile = ((id >> 3) << 1) + (slot & 1);
  const int cnt = counts[n];
  const int tile0 = tile * 64;
  if (tile0 >= cnt) return;           // block-uniform exit before any barrier
  const int mvalid = min(64, cnt - tile0);

  __shared__ __align__(16) ushort_t sX[64][256];    // 32 KB, XOR-swizzled
  __shared__ __align__(16) ushort_t sH[2][64][40];  // 10 KB double-buffer
  __shared__ ushort_t sB1[DF];        // b1 as bf16 (exact for b1==0)
  __shared__ int s_idx[64];
  __shared__ float s_ps[4][64];
  __shared__ float s_pq[4][64];
  __shared__ float s_mu[64];
  __shared__ float s_rs[64];
  // total ~47 KB

  const int tid  = threadIdx.x;
  const int wv   = tid >> 6;          // 0..7
  const int lane = tid & 63;
  const int q    = lane >> 4;
  const int lc   = lane & 15;
  const int fi   = wv & 1;            // GEMM1: f-sub (16 of the 32-chunk)
  const int mq   = wv >> 1;           // GEMM1: token quarter (16 rows)
  const int dq   = wv & 3;            // GEMM2: d-quarter (64 cols)
  const int mh   = wv >> 2;           // GEMM2: token half (32 rows)

  const ushort_t* w1f = w1f_all + (size_t)n * 262144;   // 512 KB / branch
  const ushort_t* w2f = w2f_all + (size_t)n * 262144;

  if (tid < 64) {
    int i = tile0 + tid;
    s_idx[tid] = (int)lists[n * TOK + (i < cnt ? i : tile0)];
  }
  if (tid < 256) {
    f32x4 v = *(const f32x4*)(b1 + n * DF + tid * 4);
    uint2 p;
    p.x = pack2(v.x, v.y);
    p.y = pack2(v.z, v.w);
    *(uint2*)(sB1 + tid * 4) = p;
  }
  __syncthreads();                    // B0: s_idx ready

  // ---- stage X tile 64x256 fp32 -> bf16 into sX, 16B-granule XOR swizzle
  #pragma unroll
  for (int it = 0; it < 4; ++it) {
    int flat = it * 512 + tid;
    int r = flat >> 5;                 // 0..63
    int c8 = flat & 31;                // 16B granule (8 bf16)
    const float* xp = x + (size_t)s_idx[r] * DM + c8 * 8;
    f32x4 a = *(const f32x4*)xp;
    f32x4 c = *(const f32x4*)(xp + 4);
    u32x4 p;
    p.x = pack2(a.x, a.y); p.y = pack2(a.z, a.w);
    p.z = pack2(c.x, c.y); p.w = pack2(c.z, c.w);
    *(u32x4*)(&sX[r][(c8 ^ (r & 31)) * 8]) = p;
  }
  __syncthreads();                    // B1: sX ready (read-only afterwards)

  // ---- X A-frags to regs: this wave's 16 tokens x K=256 (32 VGPR)
  bf16x8 xfrag[8];
  #pragma unroll
  for (int ks = 0; ks < 8; ++ks) {
    int row = mq * 16 + lc;
    int g = (ks * 4 + q) ^ (row & 31);
    xfrag[ks] = *(const bf16x8*)(&sX[row][g * 8]);
  }
  // no barrier needed: sX is never written again

  f32x4 yacc[2][4];       // [mi2][di]: 32 tok x 64 d (32 AGPR)
  #pragma unroll
  for (int mi2 = 0; mi2 < 2; ++mi2)
    #pragma unroll
    for (int di = 0; di < 4; ++di)
      yacc[mi2][di] = (f32x4){0.f, 0.f, 0.f, 0.f};

  bf16x8 w1r[8];          // W1 frags: loaded iter i, consumed g1(i+1)
  bf16x8 w2r[4];          // W2 frags: loaded top of iter, consumed same iter

  auto w1load = [&](int fc) {
    const ushort_t* p = w1f + (size_t)(fc * 2 + fi) * 4096 + lane * 8;
    #pragma unroll
    for (int ks = 0; ks < 8; ++ks)
      w1r[ks] = *(const bf16x8*)(p + ks * 512);
  };
  auto w2load = [&](int fc) {
    const ushort_t* p = w2f + (size_t)(fc * 4 + dq) * 2048 + lane * 8;
    #pragma unroll
    for (int di = 0; di < 4; ++di)
      w2r[di] = *(const bf16x8*)(p + di * 512);
  };

  // lgkm-only barrier: weight loads stay in flight across it.
  auto lbar = [&]() {
    __builtin_amdgcn_sched_barrier(0);
    __builtin_amdgcn_s_waitcnt(0xC07F);     // lgkmcnt(0), vmcnt untouched
    __builtin_amdgcn_s_barrier();
    __builtin_amdgcn_sched_barrier(0);
  };
  auto g1 = [&](int fc) {
    const float b1v = bf2f(sB1[fc * 32 + fi * 16 + lc]);
    f32x4 ha = (f32x4){0.f, 0.f, 0.f, 0.f};
    f32x4 hb = (f32x4){0.f, 0.f, 0.f, 0.f};
    __builtin_amdgcn_s_setprio(1);
    #pragma unroll
    for (int ks = 0; ks < 4; ++ks) {
      ha = __builtin_amdgcn_mfma_f32_16x16x32_bf16(xfrag[2 * ks],     w1r[2 * ks],     ha, 0, 0, 0);
      hb = __builtin_amdgcn_mfma_f32_16x16x32_bf16(xfrag[2 * ks + 1], w1r[2 * ks + 1], hb, 0, 0, 0);
    }
    __builtin_amdgcn_s_setprio(0);
    #pragma unroll
    for (int r4 = 0; r4 < 4; ++r4) {
      float v = ha[r4] + hb[r4] + b1v;
      v = (v > 0.f) ? v : (__expf(v) - 1.f);
      sH[fc & 1][mq * 16 + q * 4 + r4][fi * 16 + lc] = f2bf(v);
    }
  };
  auto g2 = [&](int fc) {
    const int rb = fc & 1;
    bf16x8 af0 = *(const bf16x8*)(&sH[rb][mh * 32 + lc][q * 8]);
    bf16x8 af1 = *(const bf16x8*)(&sH[rb][mh * 32 + 16 + lc][q * 8]);
    __builtin_amdgcn_s_setprio(1);
    #pragma unroll
    for (int di = 0; di < 4; ++di) {
      yacc[0][di] = __builtin_amdgcn_mfma_f32_16x16x32_bf16(af0, w2r[di], yacc[0][di], 0, 0, 0);
      yacc[1][di] = __builtin_amdgcn_mfma_f32_16x16x32_bf16(af1, w2r[di], yacc[1][di], 0, 0, 0);
    }
    __builtin_amdgcn_s_setprio(0);
  };

  // Pipeline: iter i = { lbar | w2load(i-1) [oldest] | g1(i) [waits w1r:
  // vmcnt(4)] | w1load(i+1) [newest, flows across barrier] | g2(i-1)
  // [waits w2r: vmcnt(8)] }. Fences pin phase order (r9 lesson).
  w1load(0);
  #pragma unroll 1
  for (int i = 0; i <= 32; ++i) {
    lbar();                            // publishes sH(i-1); vmem unaffected
    if (i >= 1) w2load(i - 1);
    __builtin_amdgcn_sched_barrier(0); // w2load stays oldest
    if (i < 32) g1(i);
    __builtin_amdgcn_sched_barrier(0); // w1load not hoisted above g1
    if (i + 1 < 32) w1load(i + 1);
    __builtin_amdgcn_sched_barrier(0); // w1load not sunk below g2
    if (i >= 1) g2(i - 1);
  }

  // ================= epilogue: +b2, LN stats, gamma/beta, store =============
  __syncthreads();
  float b2v[4], gv[4], bv[4];
  #pragma unroll
  for (int di = 0; di < 4; ++di) {
    int dcol = n * DM + dq * 64 + di * 16 + lc;
    b2v[di] = b2[dcol];
    gv[di]  = gamma[dcol];
    bv[di]  = beta[dcol];
  }
  #pragma unroll
  for (int mi2 = 0; mi2 < 2; ++mi2)
    #pragma unroll
    for (int di = 0; di < 4; ++di)
      #pragma unroll
      for (int r4 = 0; r4 < 4; ++r4)
        yacc[mi2][di][r4] += b2v[di];

  #pragma unroll
  for (int mi2 = 0; mi2 < 2; ++mi2) {
    #pragma unroll
    for (int r4 = 0; r4 < 4; ++r4) {
      float s = 0.f, sq = 0.f;
      #pragma unroll
      for (int di = 0; di < 4; ++di) {
        float v = yacc[mi2][di][r4];
        s += v; sq += v * v;
      }
      #pragma unroll
      for (int off = 1; off < 16; off <<= 1) {
        s  += __shfl_xor(s, off, 64);
        sq += __shfl_xor(sq, off, 64);
      }
      if (lc == 0) {
        int tok = mh * 32 + mi2 * 16 + q * 4 + r4;
        s_ps[dq][tok] = s;
        s_pq[dq][tok] = sq;
      }
    }
  }
  __syncthreads();
  if (tid < 64) {
    float s  = s_ps[0][tid] + s_ps[1][tid] + s_ps[2][tid] + s_ps[3][tid];
    float sq = s_pq[0][tid] + s_pq[1][tid] + s_pq[2][tid] + s_pq[3][tid];
    float mu = s * (1.f / 256.f);
    float var = fmaxf(sq * (1.f / 256.f) - mu * mu, 0.f);
    s_mu[tid] = mu;
    s_rs[tid] = rsqrtf(var + 1e-12f);
  }
  __syncthreads();

  #pragma unroll
  for (int mi2 = 0; mi2 < 2; ++mi2) {
    #pragma unroll
    for (int r4 = 0; r4 < 4; ++r4) {
      int tok = mh * 32 + mi2 * 16 + q * 4 + r4;
      if (tok < mvalid) {
        float mu = s_mu[tok], rs = s_rs[tok];
        size_t rowbase = (size_t)s_idx[tok] * DM + dq * 64;
        #pragma unroll
        for (int di = 0; di < 4; ++di) {
          float v = (yacc[mi2][di][r4] - mu) * rs * gv[di] + bv[di];
          out[rowbase + di * 16 + lc] = v;
        }
      }
    }
  }
}

extern "C" void kernel_launch(void* const* d_in, const int* in_sizes, int n_in,
                              void* d_out, int out_size, void* d_ws, size_t ws_size,
                              hipStream_t stream) {
  const float* x     = (const float*)d_in[0];
  const int*   b_seq = (const int*)d_in[1];
  const float* w1    = (const float*)d_in[2];
  const float* b1    = (const float*)d_in[3];
  const float* w2    = (const float*)d_in[4];
  const float* b2    = (const float*)d_in[5];
  const float* gamma = (const float*)d_in[6];
  const float* beta  = (const float*)d_in[7];
  float* out = (float*)d_out;

  int* counts = (int*)d_ws;
  ushort_t* lists = (ushort_t*)((char*)d_ws + 256);                 // 512 KB
  ushort_t* w1fb = (ushort_t*)((char*)d_ws + 256 + 512 * 1024);     // 2 MB
  ushort_t* w2fb = w1fb + (size_t)NB * DF * DM;                     // 2 MB

  hipMemsetAsync(counts, 0, 256, stream);
  // blocks [0,256): route; [256,768): W1 frag; [768,1280): W2 frag
  hipLaunchKernelGGL(prep_route_kernel, dim3(1280), dim3(256), 0, stream,
                     w1, w2, w1fb, w2fb, b_seq, counts, lists, (u32x4*)d_out);
  // 1024 tiles/branch capacity: covers any branch imbalance up to 65536
  hipLaunchKernelGGL(ffn_kernel, dim3(4096), dim3(512), 0, stream,
                     x, w1fb, b1, w2fb, b2, gamma, beta, counts, lists, out);
}

// Round 11
// 219.119 us; speedup vs baseline: 1.2278x; 1.2278x over previous
//
#include <hip/hip_runtime.h>

#define TOK 65536
#define DM 256
#define DF 1024
#define NB 4

typedef unsigned short ushort_t;
typedef unsigned int uint32;

typedef __attribute__((ext_vector_type(8))) short bf16x8;
typedef __attribute__((ext_vector_type(4))) float f32x4;
typedef __attribute__((ext_vector_type(4))) uint32 u32x4;

__device__ inline ushort_t f2bf(float f) {
  union { float f; unsigned int u; } v; v.f = f;
  unsigned int u = v.u;
  unsigned int r = (u + 0x7FFFu + ((u >> 16) & 1u)) >> 16;
  return (ushort_t)r;
}
__device__ inline float bf2f(ushort_t u) {
  union { unsigned int u; float f; } v; v.u = ((uint32)u) << 16; return v.f;
}
__device__ inline uint32 pack2(float a, float b) {
  return (uint32)f2bf(a) | ((uint32)f2bf(b) << 16);
}

// async global->LDS DMA, 16 B/lane: LDS dest = wave-uniform base + lane*16.
__device__ __forceinline__ void dma16(const ushort_t* g, ushort_t* lds) {
  __builtin_amdgcn_global_load_lds(
      (const __attribute__((address_space(1))) unsigned int*)(const void*)g,
      (__attribute__((address_space(3))) unsigned int*)(void*)lds,
      16, 0, 0);
}

// ------- kernel 0: merged route + W1 bf16 convert + W2 frag-layout ---------
// blocks [0,256): route (counts pre-zeroed via hipMemsetAsync)
// blocks [256,1280): W1 fp32 -> bf16 plain row-major (DMA-staged in ffn)
// blocks [1280,1792): W2 fp32 -> bf16 FRAGMENT layout (direct reg loads):
//  W2f[((fc*4+dq)*4+di)*512 + lane*8 + j] (per branch) =
//      W2[n][dq*64+di*16+(lane&15)][fc*32+(lane>>4)*8+j]
__global__ __launch_bounds__(256) void prep_route_kernel(
    const float* __restrict__ w1, const float* __restrict__ w2,
    ushort_t* __restrict__ w1b, ushort_t* __restrict__ w2fb,
    const int* __restrict__ b_seq, int* __restrict__ counts,
    ushort_t* __restrict__ lists, u32x4* __restrict__ out16)
{
  const int bx = blockIdx.x;
  const int tid = threadIdx.x;
  if (bx >= 1280) {
    // ---- W2 fragment-layout conversion (verified rounds 6-8)
    const int gid = (bx - 1280) * 256 + tid;   // 0..131071
    const int lane_ = gid & 63;
    const int lcq = lane_ & 15, qq = lane_ >> 4;
    int di = (gid >> 6) & 3, dqv = (gid >> 8) & 3;
    int fc = (gid >> 10) & 31, nn = gid >> 15;
    size_t src_off = (size_t)(nn * 256 + dqv * 64 + di * 16 + lcq) * 1024 + fc * 32 + qq * 8;
    const float* src = w2 + src_off;
    f32x4 a = *(const f32x4*)src;
    f32x4 c = *(const f32x4*)(src + 4);
    u32x4 p;
    p.x = pack2(a.x, a.y); p.y = pack2(a.z, a.w);
    p.z = pack2(c.x, c.y); p.w = pack2(c.z, c.w);
    *(u32x4*)(w2fb + (size_t)gid * 8) = p;
    return;
  }
  if (bx >= 256) {
    // ---- W1 plain bf16 conversion
    const int idx = (bx - 256) * 256 + tid;
    f32x4 v = *(const f32x4*)(w1 + (size_t)idx * 4);
    uint2 p;
    p.x = pack2(v.x, v.y);
    p.y = pack2(v.z, v.w);
    *(uint2*)(w1b + (size_t)idx * 4) = p;
    return;
  }
  // ---- route branch
  __shared__ int s_lpos[NB];
  __shared__ int s_lbase[NB];
  __shared__ int s_b[256];
  const int base = bx * 256;
  const int token = base + tid;
  if (tid < NB) s_lpos[tid] = 0;
  __syncthreads();
  const int b = b_seq[token];
  s_b[tid] = b;
  int my = 0;
  if (b > 0) my = atomicAdd(&s_lpos[b - 1], 1);
  __syncthreads();
  if (tid < NB) s_lbase[tid] = atomicAdd(&counts[tid], s_lpos[tid]);
  __syncthreads();
  if (b > 0) lists[(b - 1) * TOK + s_lbase[b - 1] + my] = (ushort_t)token;
  const u32x4 z = (u32x4){0u, 0u, 0u, 0u};
  #pragma unroll 4
  for (int it = 0; it < 64; ++it) {
    int flat = it * 256 + tid;
    int tl = flat >> 6;
    int j = flat & 63;
    if (s_b[tl] == 0) out16[(size_t)(base + tl) * 64 + j] = z;
  }
}

// ---------------- kernel 1: hybrid FFN + LN, single-BB interleaved body ----
// r8 (110us, best): W1 DMA->LDS (4x reuse), W2 frag direct-from-L2 single reg
// buffer, one vmcnt(0)+lgkm barrier per chunk. r10 lesson: direct-global is
// only for wave-UNIQUE data; redundant operands (W1) stay in LDS.
// This round's change (r8 counters: MfmaUtil 20%, pipes underloaded ->
// 2-phase burst alternation): the steady body had `if` guards -> multiple
// basic blocks -> the scheduler could NOT interleave g1's 8 LDS reads with
// g2's 8 MFMAs. Fix: peel i=0/i=32, steady body i=1..31 branch-free
// (redundant issue_w1((i+1)&31) at i=31 -> writes a buffer never read),
// g2(i-1) ordered BEFORE g1(i) so MFMAs cover ds_read latency.
// Waits (in-order vmcnt, r9 lesson): w2load oldest -> g2 waits vmcnt(2)
// leaving the W1 DMA (newest) in flight; ebar drains only the 2 DMA ops.
// Block = 8 waves (512 thr), M=64 tokens, 32 chunks of F=32.
//  GEMM1 wave (fi=wv&1, mq=wv>>1): 16 tok x 16 f.
//  GEMM2 wave (dq=wv&3, mh=wv>>2): 32 tok x 64 d.
// Regs: xfrag 32 + w2r 16 + yacc 32 AGPR ~ 96 unified (r8 measured).
__global__ __launch_bounds__(512, 4) void ffn_kernel(
    const float* __restrict__ x,
    const ushort_t* __restrict__ w1b_all, const float* __restrict__ b1,
    const ushort_t* __restrict__ w2f_all, const float* __restrict__ b2,
    const float* __restrict__ gamma, const float* __restrict__ beta,
    const int* __restrict__ counts, const ushort_t* __restrict__ lists,
    float* __restrict__ out)
{
  const int id = blockIdx.x;
  const int slot = id & 7;            // XCD affinity: branch n -> XCDs {2n,2n+1}
  const int n = slot >> 1;
  const int tile = ((id >> 3) << 1) + (slot & 1);
  const int cnt = counts[n];
  const int tile0 = tile * 64;
  if (tile0 >= cnt) return;           // block-uniform exit before any barrier
  const int mvalid = min(64, cnt - tile0);

  __shared__ __align__(16) ushort_t sW1[2][8192];   // 2 x 16KB (32f x 256k)
  __shared__ __align__(16) ushort_t sH[2][64][40];  // H double-buffer
  __shared__ ushort_t sB1[DF];        // b1 as bf16 (exact for b1==0)
  __shared__ int s_idx[64];
  __shared__ float s_ps[4][64];
  __shared__ float s_pq[4][64];
  __shared__ float s_mu[64];
  __shared__ float s_rs[64];
  // total ~47 KB

  ushort_t (*sX)[256] = (ushort_t (*)[256])&sW1[0][0];  // prologue alias 32KB

  const int tid  = threadIdx.x;
  const int wv   = tid >> 6;          // 0..7
  const int lane = tid & 63;
  const int q    = lane >> 4;
  const int lc   = lane & 15;
  const int fi   = wv & 1;            // GEMM1: f-sub (16 of the 32-chunk)
  const int mq   = wv >> 1;           // GEMM1: token quarter (16 rows)
  const int dq   = wv & 3;            // GEMM2: d-quarter (64 cols)
  const int mh   = wv >> 2;           // GEMM2: token half (32 rows)

  const ushort_t* w1b = w1b_all + (size_t)n * DF * DM;
  const ushort_t* w2f = w2f_all + (size_t)n * 262144;   // 512 KB / branch

  if (tid < 64) {
    int i = tile0 + tid;
    s_idx[tid] = (int)lists[n * TOK + (i < cnt ? i : tile0)];
  }
  if (tid < 256) {
    f32x4 v = *(const f32x4*)(b1 + n * DF + tid * 4);
    uint2 p;
    p.x = pack2(v.x, v.y);
    p.y = pack2(v.z, v.w);
    *(uint2*)(sB1 + tid * 4) = p;
  }
  __syncthreads();                    // B0: s_idx ready

  // ---- stage X tile 64x256 fp32 -> bf16 into sX, 16B-granule XOR swizzle
  #pragma unroll
  for (int it = 0; it < 4; ++it) {
    int flat = it * 512 + tid;
    int r = flat >> 5;                 // 0..63
    int c8 = flat & 31;                // 16B granule (8 bf16)
    const float* xp = x + (size_t)s_idx[r] * DM + c8 * 8;
    f32x4 a = *(const f32x4*)xp;
    f32x4 c = *(const f32x4*)(xp + 4);
    u32x4 p;
    p.x = pack2(a.x, a.y); p.y = pack2(a.z, a.w);
    p.z = pack2(c.x, c.y); p.w = pack2(c.z, c.w);
    *(u32x4*)(&sX[r][(c8 ^ (r & 31)) * 8]) = p;
  }
  __syncthreads();                    // B1: sX ready

  // ---- X A-frags to regs: this wave's 16 tokens x K=256 (32 VGPR)
  bf16x8 xfrag[8];
  #pragma unroll
  for (int ks = 0; ks < 8; ++ks) {
    int row = mq * 16 + lc;
    int g = (ks * 4 + q) ^ (row & 31);
    xfrag[ks] = *(const bf16x8*)(&sX[row][g * 8]);
  }
  __syncthreads();                    // B2: sX dead, W1 bufs free

  // W1 chunk fc -> sW1[fc&1]: 16 x 1KB segs over 8 waves (2/wave).
  // LDS[r][c] = G[r][c ^ r] (src-side swizzle; matches GEMM1 read).
  auto issue_w1 = [&](int fc) {
    ushort_t* dst = sW1[fc & 1];
    const ushort_t* g1p = w1b + (size_t)(fc * 32) * DM;
    #pragma unroll
    for (int j = 0; j < 2; ++j) {
      int i = wv * 2 + j;              // 0..15
      int s = i * 64 + lane;
      int r1 = s >> 5, cp1 = s & 31;
      dma16(g1p + (size_t)r1 * DM + (size_t)(cp1 ^ r1) * 8, dst + i * 512);
    }
  };
  // W2 chunk fc -> this wave's 4 frags (4KB, coalesced dwordx4 from L2)
  bf16x8 w2r[4];          // SINGLE buffer: loaded + consumed in same iter
  auto w2load = [&](int fc) {
    const ushort_t* p = w2f + (size_t)(fc * 4 + dq) * 2048 + lane * 8;
    #pragma unroll
    for (int di = 0; di < 4; ++di)
      w2r[di] = *(const bf16x8*)(p + di * 512);
  };

  f32x4 yacc[2][4];       // [mi2][di]: 32 tok x 64 d (32 AGPR)
  #pragma unroll
  for (int mi2 = 0; mi2 < 2; ++mi2)
    #pragma unroll
    for (int di = 0; di < 4; ++di)
      yacc[mi2][di] = (f32x4){0.f, 0.f, 0.f, 0.f};

  const int r1row = fi * 16 + lc;     // GEMM1 W1 local row (0..31)

  auto ebar = [&]() {
    __builtin_amdgcn_sched_barrier(0);
    __builtin_amdgcn_s_waitcnt(0x0070);     // vmcnt(0) lgkmcnt(0)
    __builtin_amdgcn_s_barrier();
    __builtin_amdgcn_sched_barrier(0);
  };
  auto g1 = [&](int fc) {
    const ushort_t* w1row = sW1[fc & 1] + r1row * 256;
    const float b1v = bf2f(sB1[fc * 32 + fi * 16 + lc]);
    f32x4 ha = (f32x4){0.f, 0.f, 0.f, 0.f};
    f32x4 hb = (f32x4){0.f, 0.f, 0.f, 0.f};
    __builtin_amdgcn_s_setprio(1);
    #pragma unroll
    for (int ks = 0; ks < 4; ++ks) {
      int cpa = ((2 * ks) * 4 + q) ^ r1row;
      int cpb = ((2 * ks + 1) * 4 + q) ^ r1row;
      bf16x8 bfa = *(const bf16x8*)(w1row + cpa * 8);
      bf16x8 bfb = *(const bf16x8*)(w1row + cpb * 8);
      ha = __builtin_amdgcn_mfma_f32_16x16x32_bf16(xfrag[2 * ks],     bfa, ha, 0, 0, 0);
      hb = __builtin_amdgcn_mfma_f32_16x16x32_bf16(xfrag[2 * ks + 1], bfb, hb, 0, 0, 0);
    }
    __builtin_amdgcn_s_setprio(0);
    #pragma unroll
    for (int r4 = 0; r4 < 4; ++r4) {
      float v = ha[r4] + hb[r4] + b1v;
      v = (v > 0.f) ? v : (__expf(v) - 1.f);
      sH[fc & 1][mq * 16 + q * 4 + r4][fi * 16 + lc] = f2bf(v);
    }
  };
  auto g2 = [&](int fc) {
    const int rb = fc & 1;
    bf16x8 af0 = *(const bf16x8*)(&sH[rb][mh * 32 + lc][q * 8]);
    bf16x8 af1 = *(const bf16x8*)(&sH[rb][mh * 32 + 16 + lc][q * 8]);
    __builtin_amdgcn_s_setprio(1);
    #pragma unroll
    for (int di = 0; di < 4; ++di) {
      yacc[0][di] = __builtin_amdgcn_mfma_f32_16x16x32_bf16(af0, w2r[di], yacc[0][di], 0, 0, 0);
      yacc[1][di] = __builtin_amdgcn_mfma_f32_16x16x32_bf16(af1, w2r[di], yacc[1][di], 0, 0, 0);
    }
    __builtin_amdgcn_s_setprio(0);
  };

  // ---- peeled prologue (i=0): no g2 yet
  issue_w1(0);
  ebar();                              // drain W1(0) (startup, uncovered)
  issue_w1(1);
  g1(0);

  // ---- steady loop i=1..31: branch-free single-BB body; g2 before g1 so
  // the scheduler hoists g1's ds_reads into g2's MFMA burst.
  #pragma unroll 1
  for (int i = 1; i < 32; ++i) {
    ebar();                            // drains W1(i) DMA; publishes sH(i-1)
    w2load(i - 1);                     // 4 vmem, oldest
    issue_w1((i + 1) & 31);            // 2 DMA, newest (i=31: redundant ch.0
                                       //   into sW1[0], never read — harmless)
    g2(i - 1);                         // af reads + 8 MFMA; waits vmcnt(2)
    g1(i);                             // 8 ds_read + 8 MFMA + ELU + sH write
  }

  // ---- peeled epilogue (i=32): last g2
  ebar();
  w2load(31);
  g2(31);

  // ================= epilogue: +b2, LN stats, gamma/beta, store =============
  __syncthreads();
  float b2v[4], gv[4], bv[4];
  #pragma unroll
  for (int di = 0; di < 4; ++di) {
    int dcol = n * DM + dq * 64 + di * 16 + lc;
    b2v[di] = b2[dcol];
    gv[di]  = gamma[dcol];
    bv[di]  = beta[dcol];
  }
  #pragma unroll
  for (int mi2 = 0; mi2 < 2; ++mi2)
    #pragma unroll
    for (int di = 0; di < 4; ++di)
      #pragma unroll
      for (int r4 = 0; r4 < 4; ++r4)
        yacc[mi2][di][r4] += b2v[di];

  #pragma unroll
  for (int mi2 = 0; mi2 < 2; ++mi2) {
    #pragma unroll
    for (int r4 = 0; r4 < 4; ++r4) {
      float s = 0.f, sq = 0.f;
      #pragma unroll
      for (int di = 0; di < 4; ++di) {
        float v = yacc[mi2][di][r4];
        s += v; sq += v * v;
      }
      #pragma unroll
      for (int off = 1; off < 16; off <<= 1) {
        s  += __shfl_xor(s, off, 64);
        sq += __shfl_xor(sq, off, 64);
      }
      if (lc == 0) {
        int tok = mh * 32 + mi2 * 16 + q * 4 + r4;
        s_ps[dq][tok] = s;
        s_pq[dq][tok] = sq;
      }
    }
  }
  __syncthreads();
  if (tid < 64) {
    float s  = s_ps[0][tid] + s_ps[1][tid] + s_ps[2][tid] + s_ps[3][tid];
    float sq = s_pq[0][tid] + s_pq[1][tid] + s_pq[2][tid] + s_pq[3][tid];
    float mu = s * (1.f / 256.f);
    float var = fmaxf(sq * (1.f / 256.f) - mu * mu, 0.f);
    s_mu[tid] = mu;
    s_rs[tid] = rsqrtf(var + 1e-12f);
  }
  __syncthreads();

  #pragma unroll
  for (int mi2 = 0; mi2 < 2; ++mi2) {
    #pragma unroll
    for (int r4 = 0; r4 < 4; ++r4) {
      int tok = mh * 32 + mi2 * 16 + q * 4 + r4;
      if (tok < mvalid) {
        float mu = s_mu[tok], rs = s_rs[tok];
        size_t rowbase = (size_t)s_idx[tok] * DM + dq * 64;
        #pragma unroll
        for (int di = 0; di < 4; ++di) {
          float v = (yacc[mi2][di][r4] - mu) * rs * gv[di] + bv[di];
          out[rowbase + di * 16 + lc] = v;
        }
      }
    }
  }
}

extern "C" void kernel_launch(void* const* d_in, const int* in_sizes, int n_in,
                              void* d_out, int out_size, void* d_ws, size_t ws_size,
                              hipStream_t stream) {
  const float* x     = (const float*)d_in[0];
  const int*   b_seq = (const int*)d_in[1];
  const float* w1    = (const float*)d_in[2];
  const float* b1    = (const float*)d_in[3];
  const float* w2    = (const float*)d_in[4];
  const float* b2    = (const float*)d_in[5];
  const float* gamma = (const float*)d_in[6];
  const float* beta  = (const float*)d_in[7];
  float* out = (float*)d_out;

  int* counts = (int*)d_ws;
  ushort_t* lists = (ushort_t*)((char*)d_ws + 256);                 // 512 KB
  ushort_t* w1b = (ushort_t*)((char*)d_ws + 256 + 512 * 1024);      // 2 MB
  ushort_t* w2fb = w1b + (size_t)NB * DF * DM;                      // 2 MB

  hipMemsetAsync(counts, 0, 256, stream);
  // blocks [0,256): route; [256,1280): W1 bf16; [1280,1792): W2 frag layout
  hipLaunchKernelGGL(prep_route_kernel, dim3(1792), dim3(256), 0, stream,
                     w1, w2, w1b, w2fb, b_seq, counts, lists, (u32x4*)d_out);
  // 1024 tiles/branch capacity: covers any branch imbalance up to 65536
  hipLaunchKernelGGL(ffn_kernel, dim3(4096), dim3(512), 0, stream,
                     x, w1b, b1, w2fb, b2, gamma, beta, counts, lists, out);
}